// Round 8
// baseline (163.121 us; speedup 1.0000x reference)
//
#include <hip/hip_runtime.h>
#include <hip/hip_bf16.h>

// ---------- types ----------
typedef __attribute__((ext_vector_type(8))) short short8;
typedef __attribute__((ext_vector_type(4))) float f32x4;

__device__ __forceinline__ short tobf(float f) {
  __hip_bfloat16 h = __float2bfloat16(f);
  return *reinterpret_cast<short*>(&h);
}

// XOR swizzle of the 16B-column index within a 128B LDS row (G4 / T2).
__device__ __forceinline__ int swz(int row) { return (row ^ (row >> 3)) & 7; }

#define GLDS16(gp, lp) __builtin_amdgcn_global_load_lds( \
    (__attribute__((address_space(1))) void*)(gp),       \
    (__attribute__((address_space(3))) void*)(lp), 16, 0, 0)

// q pre-scale folded into QKV-GEMM epilogue: S = (q*alpha)·k is then in
// log2 domain with the 1/sqrt(64) attention scale included -> attn uses exp2.
#define QSCALE 0.18033688011112042f  // 0.125 * log2(e)

// ---------- fused prep kernel ----------
__global__ __launch_bounds__(256) void prep_k(
    const float* __restrict__ x, short* __restrict__ xb,
    const float* __restrict__ Wqkv, short* __restrict__ WqkvT,
    const float* __restrict__ Wout, short* __restrict__ WoutT,
    float* __restrict__ cost, float* __restrict__ sint) {
  __shared__ float t[64][65];
  const int bx = blockIdx.x, tid = threadIdx.x;
  if (bx < 1024) {
    int base = bx * 4096 + tid * 4;
#pragma unroll
    for (int rep = 0; rep < 4; ++rep) {
      int i = base + rep * 1024;
      float4 v = *(const float4*)(x + i);
      *(short4*)(xb + i) = make_short4(tobf(v.x), tobf(v.y), tobf(v.z), tobf(v.w));
    }
  } else if (bx < 1664) {
    const float* in;
    short* out;
    int C, bb;
    if (bx < 1408) { in = Wqkv; out = WqkvT; C = 1536; bb = bx - 1024; }
    else           { in = Wout; out = WoutT; C = 1024; bb = bx - 1408; }
    const int R = 1024;
    int nc = C >> 6;
    int br = bb / nc, bc = bb % nc;
    int lr = tid >> 6, lc = tid & 63;
#pragma unroll
    for (int j = 0; j < 16; ++j) {
      int r = j * 4 + lr;
      t[r][lc] = in[(size_t)(br * 64 + r) * C + bc * 64 + lc];
    }
    __syncthreads();
#pragma unroll
    for (int j = 0; j < 16; ++j) {
      int r = j * 4 + lr;
      out[(size_t)(bc * 64 + r) * R + br * 64 + lc] = tobf(t[lc][r]);
    }
  } else {
    int t2 = (bx - 1664) * 256 + tid;  // < 65536
    int s = t2 >> 5, f = t2 & 31;
    float inv = __expf(-(float)f * (logf(50000.0f) / 32.0f));
    float a = (float)s * inv;
    cost[t2] = cosf(a);
    sint[t2] = sinf(a);
  }
}

// ---------- GEMM: C[M][N] = A[M][K](bf16) * Bt[N][K](bf16)^T + bias ----------
template <int MODE>
__global__ __launch_bounds__(256) void gemm128_k(
    const short* __restrict__ A, const short* __restrict__ Bt,
    const float* __restrict__ bias, void* __restrict__ Cout,
    int M, int N, int K,
    const float* __restrict__ cost, const float* __restrict__ sint) {
  __shared__ short As[128 * 64];
  __shared__ short Bs[128 * 64];
  const int ntile = N >> 7;
  const int bm = blockIdx.x / ntile, bn = blockIdx.x % ntile;
  const int tid = threadIdx.x, w = tid >> 6, l = tid & 63;
  const int c = l & 15, g = l >> 4;
  const int wm = w >> 1, wn = w & 1;
  const int m0 = bm * 128, n0 = bn * 128;

  f32x4 acc[4][4] = {};

  for (int k0 = 0; k0 < K; k0 += 64) {
#pragma unroll
    for (int j = 0; j < 4; ++j) {
      int rb = j * 32 + w * 8;
      int row = rb + (l >> 3);
      int colel = ((l & 7) ^ swz(row)) * 8;  // pre-swizzled source (rule #21)
      GLDS16(A + (size_t)(m0 + row) * K + k0 + colel, &As[rb * 64]);
      GLDS16(Bt + (size_t)(n0 + row) * K + k0 + colel, &Bs[rb * 64]);
    }
    __syncthreads();
#pragma unroll
    for (int kk = 0; kk < 2; ++kk) {
      short8 af[4], bf[4];
#pragma unroll
      for (int mi = 0; mi < 4; ++mi) {
        int row = wm * 64 + mi * 16 + c;
        af[mi] = *(const short8*)&As[row * 64 + ((kk * 4 + g) ^ swz(row)) * 8];
      }
#pragma unroll
      for (int ni = 0; ni < 4; ++ni) {
        int row = wn * 64 + ni * 16 + c;
        bf[ni] = *(const short8*)&Bs[row * 64 + ((kk * 4 + g) ^ swz(row)) * 8];
      }
#pragma unroll
      for (int mi = 0; mi < 4; ++mi)
#pragma unroll
        for (int ni = 0; ni < 4; ++ni)
          acc[mi][ni] = __builtin_amdgcn_mfma_f32_16x16x32_bf16(af[mi], bf[ni], acc[mi][ni], 0, 0, 0);
    }
    __syncthreads();
  }

#pragma unroll
  for (int mi = 0; mi < 4; ++mi)
#pragma unroll
    for (int r = 0; r < 4; ++r) {
      int m = m0 + wm * 64 + mi * 16 + g * 4 + r;
      int s = m & 2047;
#pragma unroll
      for (int ni = 0; ni < 4; ++ni) {
        int n = n0 + wn * 64 + ni * 16 + c;
        float v = acc[mi][ni][r] + bias[n];
        if (MODE == 0) {
          if (n < 1280) {  // q or k region: apply RoPE
            int d = n & 63, f = d & 31;
            float cs = cost[s * 32 + f], sn = sint[s * 32 + f];
            float partner = acc[mi][ni ^ 2][r] + bias[n ^ 32];
            v = (d < 32) ? (v * cs - partner * sn) : (v * cs + partner * sn);
          }
          if (n < 1024) v *= QSCALE;  // q prescale (commutes with rotation)
          ((short*)Cout)[(size_t)m * N + n] = tobf(v);
        } else {
          ((float*)Cout)[(size_t)m * N + n] = v;
        }
      }
    }
}

// ---------- V transpose: qkv v-region -> vT[b*4+hg][64 d][2048 s] ----------
__global__ __launch_bounds__(256) void vtrans_k(const short* __restrict__ qkvb,
                                                short* __restrict__ vT) {
  __shared__ short t[64][68];
  const int bx = blockIdx.x;            // bg*32 + st
  const int st = bx & 31, bg = bx >> 5; // bg = b*4+hg
  const int b = bg >> 2, hg = bg & 3;
  const int tid = threadIdx.x, lr = tid >> 6, lc = tid & 63;
  const size_t inbase = (size_t)(b * 2048 + st * 64) * 1536 + 1280 + hg * 64;
#pragma unroll
  for (int jj = 0; jj < 16; ++jj) {
    int r = jj * 4 + lr;
    t[r][lc] = qkvb[inbase + (size_t)r * 1536 + lc];
  }
  __syncthreads();
  const size_t outbase = (size_t)(bg * 64) * 2048 + st * 64;
#pragma unroll
  for (int jj = 0; jj < 16; ++jj) {
    int d = jj * 4 + lr;
    vT[outbase + (size_t)d * 2048 + lc] = t[lc][d];
  }
}

// ---------- flash attention (causal, GQA), barrier-free ----------
// Block = (b, hg, qt) x 4 waves = the 4 q-heads of one GQA group, each wave
// fully independent (no __syncthreads anywhere). Each wave owns 32 q-rows
// (2 sets of 16) and loads its K/V MFMA fragments DIRECTLY from global
// (16B/lane; the 4 waves read identical K/V tiles -> L1/L2 hits). K(j+1)
// issued after QK(j), V(j+1) after PV(j) -> latency hidden under compute by
// compiler vmcnt scheduling. P bounces through wave-private LDS (in-order DS,
// no barrier). Swapped QK^T, in-register log2-domain softmax, defer-max.
__global__ __launch_bounds__(256) void attn_k(const short* __restrict__ qkv,
                                              const short* __restrict__ vT,
                                              short* __restrict__ aout) {
  __shared__ short Ps[4][2][16 * 64];  // [wave][set] 16x64 P tile (16KB)

  const int bx = blockIdx.x;
  const int qt = 63 - (bx >> 3);       // longest blocks dispatch first
  const int rem = bx & 7;
  const int b = rem >> 2, hg = rem & 3;
  const int tid = threadIdx.x, w = tid >> 6, l = tid & 63;
  const int h = hg * 4 + w;            // this wave's q-head
  const int c = l & 15, g = l >> 4;
  const size_t qkbase = (size_t)(b * 2048) * 1536;
  const size_t vbase = (size_t)((b * 4 + hg) * 64) * 2048;
  const int nkt = (qt >> 1) + 1;

  // Q fragments: 32 q-rows = 2 sets of 16 (q = qt*32 + set*16 + c)
  short8 aq[2][2];
#pragma unroll
  for (int set = 0; set < 2; ++set)
#pragma unroll
    for (int kk = 0; kk < 2; ++kk)
      aq[set][kk] = *(const short8*)(qkv + qkbase +
          (size_t)(qt * 32 + set * 16 + c) * 1536 + h * 64 + kk * 32 + g * 8);

  // prologue: K(0), V(0) fragments direct from global
  short8 bk[2][4], bv[2][4];
#pragma unroll
  for (int kk = 0; kk < 2; ++kk)
#pragma unroll
    for (int nb = 0; nb < 4; ++nb) {
      bk[kk][nb] = *(const short8*)(qkv + qkbase + (size_t)(nb * 16 + c) * 1536 +
                                    1024 + hg * 64 + kk * 32 + g * 8);
      bv[kk][nb] = *(const short8*)(vT + vbase + (size_t)(nb * 16 + c) * 2048 +
                                    kk * 32 + g * 8);
    }

  f32x4 acco[2][4] = {};
  float mrun[2] = {-1e30f, -1e30f};
  float lrun[2] = {0.f, 0.f};

  for (int j = 0; j < nkt; ++j) {
    const bool pf = (j + 1 < nkt);
    const bool diag = (j == nkt - 1);

#pragma unroll
    for (int set = 0; set < 2; ++set) {
      // S^T = K * Q^T : lane (c,g) holds S[q=c][k=nb*16+g*4+r] (log2 domain)
      f32x4 sfr[4] = {};
      __builtin_amdgcn_s_setprio(1);
#pragma unroll
      for (int kk = 0; kk < 2; ++kk)
#pragma unroll
        for (int nb = 0; nb < 4; ++nb)
          sfr[nb] = __builtin_amdgcn_mfma_f32_16x16x32_bf16(bk[kk][nb], aq[set][kk], sfr[nb], 0, 0, 0);
      __builtin_amdgcn_s_setprio(0);

      // after the last QK use of bk: issue K(j+1) into the same registers
      // (latency hides under set1 softmax + PV; compiler emits the vmcnt)
      if (set == 1 && pf) {
#pragma unroll
        for (int kk = 0; kk < 2; ++kk)
#pragma unroll
          for (int nb = 0; nb < 4; ++nb)
            bk[kk][nb] = *(const short8*)(qkv + qkbase +
                (size_t)((j + 1) * 64 + nb * 16 + c) * 1536 + 1024 + hg * 64 + kk * 32 + g * 8);
      }

      // causal mask (diag tile only; scale folded into q)
      if (diag) {
        int qg = qt * 32 + set * 16 + c;
#pragma unroll
        for (int nb = 0; nb < 4; ++nb)
#pragma unroll
          for (int r = 0; r < 4; ++r)
            if (j * 64 + nb * 16 + g * 4 + r > qg) sfr[nb][r] = -1e30f;
      }

      // in-register online softmax, log2 domain, defer-max (T13)
      float mx = fmaxf(fmaxf(sfr[0][0], sfr[0][1]), fmaxf(sfr[0][2], sfr[0][3]));
#pragma unroll
      for (int nb = 1; nb < 4; ++nb)
        mx = fmaxf(mx, fmaxf(fmaxf(sfr[nb][0], sfr[nb][1]), fmaxf(sfr[nb][2], sfr[nb][3])));
      mx = fmaxf(mx, __shfl_xor(mx, 16, 64));
      mx = fmaxf(mx, __shfl_xor(mx, 32, 64));
      if (!__all(mx <= mrun[set] + 8.0f)) {  // rare rescale path
        float mnew = fmaxf(mrun[set], mx);
        float sc = exp2f(mrun[set] - mnew);
        mrun[set] = mnew;
        lrun[set] *= sc;
        float scb[4];
#pragma unroll
        for (int r = 0; r < 4; ++r) scb[r] = __shfl(sc, g * 4 + r, 64);
#pragma unroll
        for (int nb = 0; nb < 4; ++nb)
#pragma unroll
          for (int r = 0; r < 4; ++r) acco[set][nb][r] *= scb[r];
      }
      float rs = 0.f;
#pragma unroll
      for (int nb = 0; nb < 4; ++nb)
#pragma unroll
        for (int r = 0; r < 4; ++r) {
          float p = exp2f(sfr[nb][r] - mrun[set]);
          sfr[nb][r] = p;
          rs += p;
        }
      rs += __shfl_xor(rs, 16, 64);
      rs += __shfl_xor(rs, 32, 64);
      lrun[set] += rs;

      // P -> wave-private LDS (no barrier needed: same-wave in-order DS)
      short* Pw = &Ps[w][set][0];
#pragma unroll
      for (int nb = 0; nb < 4; ++nb) {
        short4 pv;
        pv.x = tobf(sfr[nb][0]);
        pv.y = tobf(sfr[nb][1]);
        pv.z = tobf(sfr[nb][2]);
        pv.w = tobf(sfr[nb][3]);
        int pslot = (nb * 2 + (g >> 1)) ^ swz(c);
        *(short4*)&Pw[c * 64 + pslot * 8 + (g & 1) * 4] = pv;
      }

      // PV: O[q][d] += P * V
      __builtin_amdgcn_s_setprio(1);
#pragma unroll
      for (int kk = 0; kk < 2; ++kk) {
        short8 ap = *(const short8*)&Pw[c * 64 + (((kk * 4 + g) ^ swz(c)) * 8)];
#pragma unroll
        for (int nb = 0; nb < 4; ++nb)
          acco[set][nb] = __builtin_amdgcn_mfma_f32_16x16x32_bf16(ap, bv[kk][nb], acco[set][nb], 0, 0, 0);
      }
      __builtin_amdgcn_s_setprio(0);
    }

    // after both sets' PV: issue V(j+1) (hidden under next iter's QK+softmax)
    if (pf) {
#pragma unroll
      for (int kk = 0; kk < 2; ++kk)
#pragma unroll
        for (int nb = 0; nb < 4; ++nb)
          bv[kk][nb] = *(const short8*)(vT + vbase + (size_t)(nb * 16 + c) * 2048 +
                                        (j + 1) * 64 + kk * 32 + g * 8);
    }
  }

  // epilogue: broadcast 1/l to acco row layout, store bf16
#pragma unroll
  for (int set = 0; set < 2; ++set) {
    float li = 1.0f / lrun[set];
    float lb[4];
#pragma unroll
    for (int r = 0; r < 4; ++r) lb[r] = __shfl(li, g * 4 + r, 64);
#pragma unroll
    for (int nb = 0; nb < 4; ++nb)
#pragma unroll
      for (int r = 0; r < 4; ++r) {
        int m = b * 2048 + qt * 32 + set * 16 + g * 4 + r;
        int n = h * 64 + nb * 16 + c;
        aout[(size_t)m * 1024 + n] = tobf(acco[set][nb][r] * lb[r]);
      }
  }
}

// ---------- launch ----------
extern "C" void kernel_launch(void* const* d_in, const int* in_sizes, int n_in,
                              void* d_out, int out_size, void* d_ws, size_t ws_size,
                              hipStream_t stream) {
  const float* x    = (const float*)d_in[0];
  const float* Wqkv = (const float*)d_in[1];
  const float* bqkv = (const float*)d_in[2];
  const float* Wout = (const float*)d_in[3];
  const float* bout = (const float*)d_in[4];

  char* ws = (char*)d_ws;
  short* xb    = (short*)ws; ws += 8388608;    // x bf16 [4096][1024]
  short* WqkvT = (short*)ws; ws += 3145728;    // [1536][1024] bf16
  short* WoutT = (short*)ws; ws += 2097152;    // [1024][1024] bf16
  short* qkvb  = (short*)ws; ws += 12582912;   // [4096][1536] bf16 (post-RoPE)
  short* attnb = (short*)ws; ws += 8388608;    // [4096][1024] bf16
  short* vTb   = (short*)ws; ws += 2097152;    // [8][64][2048] bf16 (V transposed)
  float* cost  = (float*)ws; ws += 262144;     // [2048][32]
  float* sint  = (float*)ws; ws += 262144;

  prep_k<<<1920, 256, 0, stream>>>(x, xb, Wqkv, WqkvT, Wout, WoutT, cost, sint);
  gemm128_k<0><<<384, 256, 0, stream>>>(xb, WqkvT, bqkv, (void*)qkvb, 4096, 1536, 1024, cost, sint);
  vtrans_k<<<256, 256, 0, stream>>>(qkvb, vTb);
  attn_k<<<512, 256, 0, stream>>>(qkvb, vTb, attnb);
  gemm128_k<1><<<256, 256, 0, stream>>>(attnb, WoutT, bout, d_out, 4096, 1024, 1024, cost, sint);
}

// Round 9
// 143.410 us; speedup vs baseline: 1.1374x; 1.1374x over previous
//
#include <hip/hip_runtime.h>
#include <hip/hip_bf16.h>

// ---------- types ----------
typedef __attribute__((ext_vector_type(8))) short short8;
typedef __attribute__((ext_vector_type(4))) float f32x4;

__device__ __forceinline__ short tobf(float f) {
  __hip_bfloat16 h = __float2bfloat16(f);
  return *reinterpret_cast<short*>(&h);
}

// XOR swizzle of the 16B-column index within a 128B LDS row (G4 / T2).
__device__ __forceinline__ int swz(int row) { return (row ^ (row >> 3)) & 7; }

#define GLDS16(gp, lp) __builtin_amdgcn_global_load_lds( \
    (__attribute__((address_space(1))) void*)(gp),       \
    (__attribute__((address_space(3))) void*)(lp), 16, 0, 0)

// q pre-scale folded into QKV-GEMM epilogue: S = (q*alpha)·k is then in
// log2 domain with the 1/sqrt(64) attention scale included -> attn uses exp2.
#define QSCALE 0.18033688011112042f  // 0.125 * log2(e)

// ---------- fused prep kernel ----------
__global__ __launch_bounds__(256) void prep_k(
    const float* __restrict__ x, short* __restrict__ xb,
    const float* __restrict__ Wqkv, short* __restrict__ WqkvT,
    const float* __restrict__ Wout, short* __restrict__ WoutT,
    float* __restrict__ cost, float* __restrict__ sint) {
  __shared__ float t[64][65];
  const int bx = blockIdx.x, tid = threadIdx.x;
  if (bx < 1024) {
    int base = bx * 4096 + tid * 4;
#pragma unroll
    for (int rep = 0; rep < 4; ++rep) {
      int i = base + rep * 1024;
      float4 v = *(const float4*)(x + i);
      *(short4*)(xb + i) = make_short4(tobf(v.x), tobf(v.y), tobf(v.z), tobf(v.w));
    }
  } else if (bx < 1664) {
    const float* in;
    short* out;
    int C, bb;
    if (bx < 1408) { in = Wqkv; out = WqkvT; C = 1536; bb = bx - 1024; }
    else           { in = Wout; out = WoutT; C = 1024; bb = bx - 1408; }
    const int R = 1024;
    int nc = C >> 6;
    int br = bb / nc, bc = bb % nc;
    int lr = tid >> 6, lc = tid & 63;
#pragma unroll
    for (int j = 0; j < 16; ++j) {
      int r = j * 4 + lr;
      t[r][lc] = in[(size_t)(br * 64 + r) * C + bc * 64 + lc];
    }
    __syncthreads();
#pragma unroll
    for (int j = 0; j < 16; ++j) {
      int r = j * 4 + lr;
      out[(size_t)(bc * 64 + r) * R + br * 64 + lc] = tobf(t[lc][r]);
    }
  } else {
    int t2 = (bx - 1664) * 256 + tid;  // < 65536
    int s = t2 >> 5, f = t2 & 31;
    float inv = __expf(-(float)f * (logf(50000.0f) / 32.0f));
    float a = (float)s * inv;
    cost[t2] = cosf(a);
    sint[t2] = sinf(a);
  }
}

// ---------- GEMM: C[M][N] = A[M][K](bf16) * Bt[N][K](bf16)^T + bias ----------
template <int MODE>
__global__ __launch_bounds__(256) void gemm128_k(
    const short* __restrict__ A, const short* __restrict__ Bt,
    const float* __restrict__ bias, void* __restrict__ Cout,
    int M, int N, int K,
    const float* __restrict__ cost, const float* __restrict__ sint) {
  __shared__ short As[128 * 64];
  __shared__ short Bs[128 * 64];
  const int ntile = N >> 7;
  const int bm = blockIdx.x / ntile, bn = blockIdx.x % ntile;
  const int tid = threadIdx.x, w = tid >> 6, l = tid & 63;
  const int c = l & 15, g = l >> 4;
  const int wm = w >> 1, wn = w & 1;
  const int m0 = bm * 128, n0 = bn * 128;

  f32x4 acc[4][4] = {};

  for (int k0 = 0; k0 < K; k0 += 64) {
#pragma unroll
    for (int j = 0; j < 4; ++j) {
      int rb = j * 32 + w * 8;
      int row = rb + (l >> 3);
      int colel = ((l & 7) ^ swz(row)) * 8;  // pre-swizzled source (rule #21)
      GLDS16(A + (size_t)(m0 + row) * K + k0 + colel, &As[rb * 64]);
      GLDS16(Bt + (size_t)(n0 + row) * K + k0 + colel, &Bs[rb * 64]);
    }
    __syncthreads();
#pragma unroll
    for (int kk = 0; kk < 2; ++kk) {
      short8 af[4], bf[4];
#pragma unroll
      for (int mi = 0; mi < 4; ++mi) {
        int row = wm * 64 + mi * 16 + c;
        af[mi] = *(const short8*)&As[row * 64 + ((kk * 4 + g) ^ swz(row)) * 8];
      }
#pragma unroll
      for (int ni = 0; ni < 4; ++ni) {
        int row = wn * 64 + ni * 16 + c;
        bf[ni] = *(const short8*)&Bs[row * 64 + ((kk * 4 + g) ^ swz(row)) * 8];
      }
#pragma unroll
      for (int mi = 0; mi < 4; ++mi)
#pragma unroll
        for (int ni = 0; ni < 4; ++ni)
          acc[mi][ni] = __builtin_amdgcn_mfma_f32_16x16x32_bf16(af[mi], bf[ni], acc[mi][ni], 0, 0, 0);
    }
    __syncthreads();
  }

#pragma unroll
  for (int mi = 0; mi < 4; ++mi)
#pragma unroll
    for (int r = 0; r < 4; ++r) {
      int m = m0 + wm * 64 + mi * 16 + g * 4 + r;
      int s = m & 2047;
#pragma unroll
      for (int ni = 0; ni < 4; ++ni) {
        int n = n0 + wn * 64 + ni * 16 + c;
        float v = acc[mi][ni][r] + bias[n];
        if (MODE == 0) {
          if (n < 1280) {  // q or k region: apply RoPE
            int d = n & 63, f = d & 31;
            float cs = cost[s * 32 + f], sn = sint[s * 32 + f];
            float partner = acc[mi][ni ^ 2][r] + bias[n ^ 32];
            v = (d < 32) ? (v * cs - partner * sn) : (v * cs + partner * sn);
          }
          if (n < 1024) v *= QSCALE;  // q prescale (commutes with rotation)
          ((short*)Cout)[(size_t)m * N + n] = tobf(v);
        } else {
          ((float*)Cout)[(size_t)m * N + n] = v;
        }
      }
    }
}

// ---------- V transpose: qkv v-region -> vT[b*4+hg][64 d][2048 s] ----------
__global__ __launch_bounds__(256) void vtrans_k(const short* __restrict__ qkvb,
                                                short* __restrict__ vT) {
  __shared__ short t[64][68];
  const int bx = blockIdx.x;            // bg*32 + st
  const int st = bx & 31, bg = bx >> 5; // bg = b*4+hg
  const int b = bg >> 2, hg = bg & 3;
  const int tid = threadIdx.x, lr = tid >> 6, lc = tid & 63;
  const size_t inbase = (size_t)(b * 2048 + st * 64) * 1536 + 1280 + hg * 64;
#pragma unroll
  for (int jj = 0; jj < 16; ++jj) {
    int r = jj * 4 + lr;
    t[r][lc] = qkvb[inbase + (size_t)r * 1536 + lc];
  }
  __syncthreads();
  const size_t outbase = (size_t)(bg * 64) * 2048 + st * 64;
#pragma unroll
  for (int jj = 0; jj < 16; ++jj) {
    int d = jj * 4 + lr;
    vT[outbase + (size_t)d * 2048 + lc] = t[lc][d];
  }
}

// ---------- flash attention (causal, GQA) ----------
// R6 staging structure (GLDS double-buffered K and V^T, ONE barrier/iter),
// restructured to 128-thread blocks (2 waves): each wave owns 32 q-rows as
// 2 independent 16-row sets -> 32 MFMA per iter per wave against the same
// 16 hoisted LDS fragment reads (2x R6's MFMA:overhead ratio), and set-level
// ILP (set1 QK MFMAs in flight under set0 softmax VALU). LDS 36KB ->
// 4 blocks/CU. Swapped QK^T, in-register log2-domain softmax, defer-max.
__global__ __launch_bounds__(128) void attn_k(const short* __restrict__ qkv,
                                              const short* __restrict__ vT,
                                              short* __restrict__ aout) {
  __shared__ short Ks[2][64 * 64];  // 16KB: K tiles (double-buffered)
  __shared__ short Vt[2][64 * 64];  // 16KB: V^T tiles
  __shared__ short Ps[2][16 * 64];  // 4KB: per-wave P tile (reused across sets)

  const int bx = blockIdx.x;
  const int qt = 31 - (bx >> 5);     // longest blocks dispatch first
  const int bh = bx & 31;
  const int b = bh >> 4, h = bh & 15, hg = h >> 2;
  const int tid = threadIdx.x, w = tid >> 6, l = tid & 63;
  const int c = l & 15, g = l >> 4;
  const size_t rowbase = (size_t)(b * 2048) * 1536;
  const size_t vbase = (size_t)((b * 4 + hg) * 64) * 2048;

  // Q fragments direct from global (one-time; q = qt*64 + w*32 + set*16 + c)
  short8 aq[2][2];
#pragma unroll
  for (int set = 0; set < 2; ++set)
#pragma unroll
    for (int kk = 0; kk < 2; ++kk)
      aq[set][kk] = *(const short8*)(qkv + rowbase +
          (size_t)(qt * 64 + w * 32 + set * 16 + c) * 1536 + h * 64 + kk * 32 + g * 8);

  // ---- prologue: stage K(0) -> Ks[0], V^T(0) -> Vt[0] ----
#pragma unroll
  for (int i = 0; i < 4; ++i) {
    int rb = i * 16 + w * 8;
    int row = rb + (l >> 3);
    int colel = ((l & 7) ^ swz(row)) * 8;
    GLDS16(qkv + rowbase + (size_t)row * 1536 + 1024 + hg * 64 + colel, &Ks[0][rb * 64]);
    GLDS16(vT + vbase + (size_t)row * 2048 + colel, &Vt[0][rb * 64]);
  }
  __syncthreads();

  f32x4 acco[2][4] = {};
  float mrun[2] = {-1e30f, -1e30f};
  float lrun[2] = {0.f, 0.f};
  short* Pw = &Ps[w][0];

  for (int j = 0; j <= qt; ++j) {
    const int cur = j & 1, nxt = cur ^ 1;
    const bool pf = (j < qt);

    if (pf) {  // issue next-tile loads BEFORE compute (landed by end-of-iter barrier)
#pragma unroll
      for (int i = 0; i < 4; ++i) {
        int rb = i * 16 + w * 8;
        int row = rb + (l >> 3);
        int colel = ((l & 7) ^ swz(row)) * 8;
        GLDS16(qkv + rowbase + (size_t)((j + 1) * 64 + row) * 1536 + 1024 + hg * 64 + colel,
               &Ks[nxt][rb * 64]);
        GLDS16(vT + vbase + (size_t)row * 2048 + (j + 1) * 64 + colel, &Vt[nxt][rb * 64]);
      }
    }

    // hoisted K/V fragment reads (shared by both sets)
    short8 bk[2][4], bv[2][4];
#pragma unroll
    for (int kk = 0; kk < 2; ++kk)
#pragma unroll
      for (int nb = 0; nb < 4; ++nb) {
        int row = nb * 16 + c;
        int cs = ((kk * 4 + g) ^ swz(row)) * 8;
        bk[kk][nb] = *(const short8*)&Ks[cur][row * 64 + cs];
        bv[kk][nb] = *(const short8*)&Vt[cur][row * 64 + cs];
      }

    // QK both sets: S^T = K * Q^T, lane (c,g) holds S[q=..+c][k=nb*16+g*4+r]
    f32x4 sfr[2][4] = {};
    __builtin_amdgcn_s_setprio(1);
#pragma unroll
    for (int set = 0; set < 2; ++set)
#pragma unroll
      for (int kk = 0; kk < 2; ++kk)
#pragma unroll
        for (int nb = 0; nb < 4; ++nb)
          sfr[set][nb] = __builtin_amdgcn_mfma_f32_16x16x32_bf16(
              bk[kk][nb], aq[set][kk], sfr[set][nb], 0, 0, 0);
    __builtin_amdgcn_s_setprio(0);

    // causal mask (diag tile only; scale folded into q)
    if (j == qt) {
#pragma unroll
      for (int set = 0; set < 2; ++set) {
        int qloc = w * 32 + set * 16 + c;
#pragma unroll
        for (int nb = 0; nb < 4; ++nb)
#pragma unroll
          for (int r = 0; r < 4; ++r)
            if (nb * 16 + g * 4 + r > qloc) sfr[set][nb][r] = -1e30f;
      }
    }

    // in-register online softmax (both sets; independent -> ILP), log2 domain
#pragma unroll
    for (int set = 0; set < 2; ++set) {
      float mx = fmaxf(fmaxf(sfr[set][0][0], sfr[set][0][1]),
                       fmaxf(sfr[set][0][2], sfr[set][0][3]));
#pragma unroll
      for (int nb = 1; nb < 4; ++nb)
        mx = fmaxf(mx, fmaxf(fmaxf(sfr[set][nb][0], sfr[set][nb][1]),
                             fmaxf(sfr[set][nb][2], sfr[set][nb][3])));
      mx = fmaxf(mx, __shfl_xor(mx, 16, 64));
      mx = fmaxf(mx, __shfl_xor(mx, 32, 64));
      if (!__all(mx <= mrun[set] + 8.0f)) {  // rare rescale path (T13)
        float mnew = fmaxf(mrun[set], mx);
        float sc = exp2f(mrun[set] - mnew);
        mrun[set] = mnew;
        lrun[set] *= sc;
        float scb[4];
#pragma unroll
        for (int r = 0; r < 4; ++r) scb[r] = __shfl(sc, g * 4 + r, 64);
#pragma unroll
        for (int nb = 0; nb < 4; ++nb)
#pragma unroll
          for (int r = 0; r < 4; ++r) acco[set][nb][r] *= scb[r];
      }
      float rs = 0.f;
#pragma unroll
      for (int nb = 0; nb < 4; ++nb)
#pragma unroll
        for (int r = 0; r < 4; ++r) {
          float p = exp2f(sfr[set][nb][r] - mrun[set]);
          sfr[set][nb][r] = p;
          rs += p;
        }
      rs += __shfl_xor(rs, 16, 64);
      rs += __shfl_xor(rs, 32, 64);
      lrun[set] += rs;
    }

    // P bounce + PV per set (Pw reused: same-wave in-order DS is safe)
#pragma unroll
    for (int set = 0; set < 2; ++set) {
#pragma unroll
      for (int nb = 0; nb < 4; ++nb) {
        short4 pv;
        pv.x = tobf(sfr[set][nb][0]);
        pv.y = tobf(sfr[set][nb][1]);
        pv.z = tobf(sfr[set][nb][2]);
        pv.w = tobf(sfr[set][nb][3]);
        int pslot = (nb * 2 + (g >> 1)) ^ swz(c);
        *(short4*)&Pw[c * 64 + pslot * 8 + (g & 1) * 4] = pv;
      }
      __builtin_amdgcn_s_setprio(1);
#pragma unroll
      for (int kk = 0; kk < 2; ++kk) {
        short8 ap = *(const short8*)&Pw[c * 64 + (((kk * 4 + g) ^ swz(c)) * 8)];
#pragma unroll
        for (int nb = 0; nb < 4; ++nb)
          acco[set][nb] = __builtin_amdgcn_mfma_f32_16x16x32_bf16(ap, bv[kk][nb], acco[set][nb], 0, 0, 0);
      }
      __builtin_amdgcn_s_setprio(0);
    }

    __syncthreads();  // K(j+1)/V(j+1) landed (vmcnt drain); cur-buffer reads done
  }

  // epilogue: broadcast 1/l to acco row layout, store bf16
#pragma unroll
  for (int set = 0; set < 2; ++set) {
    float li = 1.0f / lrun[set];
    float lb[4];
#pragma unroll
    for (int r = 0; r < 4; ++r) lb[r] = __shfl(li, g * 4 + r, 64);
#pragma unroll
    for (int nb = 0; nb < 4; ++nb)
#pragma unroll
      for (int r = 0; r < 4; ++r) {
        int m = b * 2048 + qt * 64 + w * 32 + set * 16 + g * 4 + r;
        int n = h * 64 + nb * 16 + c;
        aout[(size_t)m * 1024 + n] = tobf(acco[set][nb][r] * lb[r]);
      }
  }
}

// ---------- launch ----------
extern "C" void kernel_launch(void* const* d_in, const int* in_sizes, int n_in,
                              void* d_out, int out_size, void* d_ws, size_t ws_size,
                              hipStream_t stream) {
  const float* x    = (const float*)d_in[0];
  const float* Wqkv = (const float*)d_in[1];
  const float* bqkv = (const float*)d_in[2];
  const float* Wout = (const float*)d_in[3];
  const float* bout = (const float*)d_in[4];

  char* ws = (char*)d_ws;
  short* xb    = (short*)ws; ws += 8388608;    // x bf16 [4096][1024]
  short* WqkvT = (short*)ws; ws += 3145728;    // [1536][1024] bf16
  short* WoutT = (short*)ws; ws += 2097152;    // [1024][1024] bf16
  short* qkvb  = (short*)ws; ws += 12582912;   // [4096][1536] bf16 (post-RoPE)
  short* attnb = (short*)ws; ws += 8388608;    // [4096][1024] bf16
  short* vTb   = (short*)ws; ws += 2097152;    // [8][64][2048] bf16 (V transposed)
  float* cost  = (float*)ws; ws += 262144;     // [2048][32]
  float* sint  = (float*)ws; ws += 262144;

  prep_k<<<1920, 256, 0, stream>>>(x, xb, Wqkv, WqkvT, Wout, WoutT, cost, sint);
  gemm128_k<0><<<384, 256, 0, stream>>>(xb, WqkvT, bqkv, (void*)qkvb, 4096, 1536, 1024, cost, sint);
  vtrans_k<<<256, 256, 0, stream>>>(qkvb, vTb);
  attn_k<<<1024, 128, 0, stream>>>(qkvb, vTb, attnb);
  gemm128_k<1><<<256, 256, 0, stream>>>(attnb, WoutT, bout, d_out, 4096, 1024, 1024, cost, sint);
}

// Round 10
// 129.486 us; speedup vs baseline: 1.2598x; 1.1075x over previous
//
#include <hip/hip_runtime.h>
#include <hip/hip_bf16.h>

// ---------- types ----------
typedef __attribute__((ext_vector_type(8))) short short8;
typedef __attribute__((ext_vector_type(4))) float f32x4;

__device__ __forceinline__ short tobf(float f) {
  __hip_bfloat16 h = __float2bfloat16(f);
  return *reinterpret_cast<short*>(&h);
}

// XOR swizzle of the 16B-column index within a 128B LDS row (G4 / T2).
__device__ __forceinline__ int swz(int row) { return (row ^ (row >> 3)) & 7; }

#define GLDS16(gp, lp) __builtin_amdgcn_global_load_lds( \
    (__attribute__((address_space(1))) void*)(gp),       \
    (__attribute__((address_space(3))) void*)(lp), 16, 0, 0)

// q pre-scale folded into QKV-GEMM epilogue: S = (q*alpha)·k is then in
// log2 domain with the 1/sqrt(64) attention scale included -> attn uses exp2.
#define QSCALE 0.18033688011112042f  // 0.125 * log2(e)

// ---------- fused prep kernel ----------
__global__ __launch_bounds__(256) void prep_k(
    const float* __restrict__ x, short* __restrict__ xb,
    const float* __restrict__ Wqkv, short* __restrict__ WqkvT,
    const float* __restrict__ Wout, short* __restrict__ WoutT,
    float* __restrict__ cost, float* __restrict__ sint) {
  __shared__ float t[64][65];
  const int bx = blockIdx.x, tid = threadIdx.x;
  if (bx < 1024) {
    int base = bx * 4096 + tid * 4;
#pragma unroll
    for (int rep = 0; rep < 4; ++rep) {
      int i = base + rep * 1024;
      float4 v = *(const float4*)(x + i);
      *(short4*)(xb + i) = make_short4(tobf(v.x), tobf(v.y), tobf(v.z), tobf(v.w));
    }
  } else if (bx < 1664) {
    const float* in;
    short* out;
    int C, bb;
    if (bx < 1408) { in = Wqkv; out = WqkvT; C = 1536; bb = bx - 1024; }
    else           { in = Wout; out = WoutT; C = 1024; bb = bx - 1408; }
    const int R = 1024;
    int nc = C >> 6;
    int br = bb / nc, bc = bb % nc;
    int lr = tid >> 6, lc = tid & 63;
#pragma unroll
    for (int j = 0; j < 16; ++j) {
      int r = j * 4 + lr;
      t[r][lc] = in[(size_t)(br * 64 + r) * C + bc * 64 + lc];
    }
    __syncthreads();
#pragma unroll
    for (int j = 0; j < 16; ++j) {
      int r = j * 4 + lr;
      out[(size_t)(bc * 64 + r) * R + br * 64 + lc] = tobf(t[lc][r]);
    }
  } else {
    int t2 = (bx - 1664) * 256 + tid;  // < 65536
    int s = t2 >> 5, f = t2 & 31;
    float inv = __expf(-(float)f * (logf(50000.0f) / 32.0f));
    float a = (float)s * inv;
    cost[t2] = cosf(a);
    sint[t2] = sinf(a);
  }
}

// ---------- GEMM: C[M][N] = A[M][K](bf16) * Bt[N][K](bf16)^T + bias ----------
template <int MODE>
__global__ __launch_bounds__(256) void gemm128_k(
    const short* __restrict__ A, const short* __restrict__ Bt,
    const float* __restrict__ bias, void* __restrict__ Cout,
    int M, int N, int K,
    const float* __restrict__ cost, const float* __restrict__ sint) {
  __shared__ short As[128 * 64];
  __shared__ short Bs[128 * 64];
  const int ntile = N >> 7;
  const int bm = blockIdx.x / ntile, bn = blockIdx.x % ntile;
  const int tid = threadIdx.x, w = tid >> 6, l = tid & 63;
  const int c = l & 15, g = l >> 4;
  const int wm = w >> 1, wn = w & 1;
  const int m0 = bm * 128, n0 = bn * 128;

  f32x4 acc[4][4] = {};

  for (int k0 = 0; k0 < K; k0 += 64) {
#pragma unroll
    for (int j = 0; j < 4; ++j) {
      int rb = j * 32 + w * 8;
      int row = rb + (l >> 3);
      int colel = ((l & 7) ^ swz(row)) * 8;  // pre-swizzled source (rule #21)
      GLDS16(A + (size_t)(m0 + row) * K + k0 + colel, &As[rb * 64]);
      GLDS16(Bt + (size_t)(n0 + row) * K + k0 + colel, &Bs[rb * 64]);
    }
    __syncthreads();
#pragma unroll
    for (int kk = 0; kk < 2; ++kk) {
      short8 af[4], bf[4];
#pragma unroll
      for (int mi = 0; mi < 4; ++mi) {
        int row = wm * 64 + mi * 16 + c;
        af[mi] = *(const short8*)&As[row * 64 + ((kk * 4 + g) ^ swz(row)) * 8];
      }
#pragma unroll
      for (int ni = 0; ni < 4; ++ni) {
        int row = wn * 64 + ni * 16 + c;
        bf[ni] = *(const short8*)&Bs[row * 64 + ((kk * 4 + g) ^ swz(row)) * 8];
      }
#pragma unroll
      for (int mi = 0; mi < 4; ++mi)
#pragma unroll
        for (int ni = 0; ni < 4; ++ni)
          acc[mi][ni] = __builtin_amdgcn_mfma_f32_16x16x32_bf16(af[mi], bf[ni], acc[mi][ni], 0, 0, 0);
    }
    __syncthreads();
  }

#pragma unroll
  for (int mi = 0; mi < 4; ++mi)
#pragma unroll
    for (int r = 0; r < 4; ++r) {
      int m = m0 + wm * 64 + mi * 16 + g * 4 + r;
      int s = m & 2047;
#pragma unroll
      for (int ni = 0; ni < 4; ++ni) {
        int n = n0 + wn * 64 + ni * 16 + c;
        float v = acc[mi][ni][r] + bias[n];
        if (MODE == 0) {
          if (n < 1280) {  // q or k region: apply RoPE
            int d = n & 63, f = d & 31;
            float cs = cost[s * 32 + f], sn = sint[s * 32 + f];
            float partner = acc[mi][ni ^ 2][r] + bias[n ^ 32];
            v = (d < 32) ? (v * cs - partner * sn) : (v * cs + partner * sn);
          }
          if (n < 1024) v *= QSCALE;  // q prescale (commutes with rotation)
          ((short*)Cout)[(size_t)m * N + n] = tobf(v);
        } else {
          ((float*)Cout)[(size_t)m * N + n] = v;
        }
      }
    }
}

// ---------- V transpose: qkv v-region -> vT[b*4+hg][64 d][2048 s] ----------
__global__ __launch_bounds__(256) void vtrans_k(const short* __restrict__ qkvb,
                                                short* __restrict__ vT) {
  __shared__ short t[64][68];
  const int bx = blockIdx.x;            // bg*32 + st
  const int st = bx & 31, bg = bx >> 5; // bg = b*4+hg
  const int b = bg >> 2, hg = bg & 3;
  const int tid = threadIdx.x, lr = tid >> 6, lc = tid & 63;
  const size_t inbase = (size_t)(b * 2048 + st * 64) * 1536 + 1280 + hg * 64;
#pragma unroll
  for (int jj = 0; jj < 16; ++jj) {
    int r = jj * 4 + lr;
    t[r][lc] = qkvb[inbase + (size_t)r * 1536 + lc];
  }
  __syncthreads();
  const size_t outbase = (size_t)(bg * 64) * 2048 + st * 64;
#pragma unroll
  for (int jj = 0; jj < 16; ++jj) {
    int d = jj * 4 + lr;
    vT[outbase + (size_t)d * 2048 + lc] = t[lc][d];
  }
}

// ---------- flash attention (causal, GQA) ----------
// R6 structure + T4 counted-vmcnt pipeline: triple-buffered K/V^T staged by
// global_load_lds at prefetch distance 2; per-iter raw s_barrier with
// s_waitcnt vmcnt(4) (tile j+1's 4-load batch done, tile j+2's stays in
// flight) -- never drain to 0 in the loop (the m97-stall fix). 4 waves x
// 16 q-rows, swapped QK^T, in-register log2-domain softmax, defer-max.
__global__ __launch_bounds__(256) void attn_k(const short* __restrict__ qkv,
                                              const short* __restrict__ vT,
                                              short* __restrict__ aout) {
  __shared__ short Ks3[3][64 * 64];  // 24KB: K tiles (triple-buffered)
  __shared__ short Vt3[3][64 * 64];  // 24KB: V^T tiles
  __shared__ short Ps[4][16 * 64];   // 8KB: per-wave P tile (also Q staging)

  const int bx = blockIdx.x;
  const int qt = 31 - (bx >> 5);     // longest blocks dispatch first
  const int bh = bx & 31;
  const int b = bh >> 4, h = bh & 15, hg = h >> 2;
  const int tid = threadIdx.x, w = tid >> 6, l = tid & 63;
  const int c = l & 15, g = l >> 4;
  const size_t rowbase = (size_t)(b * 2048) * 1536;

  // per-thread staging offsets (loop-invariant)
  const int i0row = w * 16 + (l >> 3);
  const int i1row = w * 16 + 8 + (l >> 3);
  const int c0 = ((l & 7) ^ swz(i0row)) * 8;
  const int c1 = ((l & 7) ^ swz(i1row)) * 8;
  const size_t k0off = (size_t)i0row * 1536 + c0;
  const size_t k1off = (size_t)i1row * 1536 + c1;
  const size_t v0off = (size_t)i0row * 2048 + c0;
  const size_t v1off = (size_t)i1row * 2048 + c1;
  const int lds0 = (w * 16) * 64;
  const int lds1 = (w * 16 + 8) * 64;
  const short* kbase = qkv + rowbase + 1024 + hg * 64;
  const short* vbase_p = vT + (size_t)((b * 4 + hg) * 64) * 2048;

  // ---- stage Q (64 rows x 64 d) into Ps; read Q fragments ----
  {
    short* Qs = &Ps[0][0];
    const short* qb = qkv + rowbase + (size_t)(qt * 64) * 1536 + h * 64;
    GLDS16(qb + k0off, Qs + lds0);
    GLDS16(qb + k1off, Qs + lds1);
    __syncthreads();
  }
  short8 aq[2];
#pragma unroll
  for (int kk = 0; kk < 2; ++kk) {
    int row = w * 16 + c;
    aq[kk] = *(const short8*)&Ps[0][0 + row * 64 + ((kk * 4 + g) ^ swz(row)) * 8];
  }
  asm volatile("s_waitcnt lgkmcnt(0)" ::: "memory");  // aq reads done before reuse
  __syncthreads();

  // ---- prologue: issue tiles 0 and 1 ----
  GLDS16(kbase + k0off, &Ks3[0][lds0]);
  GLDS16(kbase + k1off, &Ks3[0][lds1]);
  GLDS16(vbase_p + v0off, &Vt3[0][lds0]);
  GLDS16(vbase_p + v1off, &Vt3[0][lds1]);
  if (qt >= 1) {
    GLDS16(kbase + 98304 + k0off, &Ks3[1][lds0]);
    GLDS16(kbase + 98304 + k1off, &Ks3[1][lds1]);
    GLDS16(vbase_p + 64 + v0off, &Vt3[1][lds0]);
    GLDS16(vbase_p + 64 + v1off, &Vt3[1][lds1]);
    asm volatile("s_waitcnt vmcnt(4)" ::: "memory");
  } else {
    asm volatile("s_waitcnt vmcnt(0)" ::: "memory");
  }
  __builtin_amdgcn_s_barrier();
  __builtin_amdgcn_sched_barrier(0);

  f32x4 acco[4] = {};
  float mrun = -1e30f, lrun = 0.f;
  short* Pw = &Ps[w][0];
  int cur = 0, s2 = 2;
  const short* pk2 = kbase + 2 * 98304;
  const short* pv2 = vbase_p + 2 * 64;

  for (int j = 0; j <= qt; ++j) {
    const bool pf2 = (j + 2 <= qt);
    if (pf2) {  // issue tile j+2 (stays in flight across this iter's barrier)
      GLDS16(pk2 + k0off, &Ks3[s2][lds0]);
      GLDS16(pk2 + k1off, &Ks3[s2][lds1]);
      GLDS16(pv2 + v0off, &Vt3[s2][lds0]);
      GLDS16(pv2 + v1off, &Vt3[s2][lds1]);
    }

    // hoisted K/V fragment reads
    short8 bk[2][4], bv[2][4];
#pragma unroll
    for (int kk = 0; kk < 2; ++kk)
#pragma unroll
      for (int nb = 0; nb < 4; ++nb) {
        int row = nb * 16 + c;
        int cs = ((kk * 4 + g) ^ swz(row)) * 8;
        bk[kk][nb] = *(const short8*)&Ks3[cur][row * 64 + cs];
        bv[kk][nb] = *(const short8*)&Vt3[cur][row * 64 + cs];
      }

    // S^T = K * Q^T : lane (c,g) holds S[q=c][k=nb*16+g*4+r] (log2 domain)
    f32x4 sfr[4] = {};
    __builtin_amdgcn_s_setprio(1);
#pragma unroll
    for (int kk = 0; kk < 2; ++kk)
#pragma unroll
      for (int nb = 0; nb < 4; ++nb)
        sfr[nb] = __builtin_amdgcn_mfma_f32_16x16x32_bf16(bk[kk][nb], aq[kk], sfr[nb], 0, 0, 0);
    __builtin_amdgcn_s_setprio(0);

    // causal mask (diag tile only; scale folded into q)
    if (j == qt) {
#pragma unroll
      for (int nb = 0; nb < 4; ++nb)
#pragma unroll
        for (int r = 0; r < 4; ++r)
          if (nb * 16 + g * 4 + r > w * 16 + c) sfr[nb][r] = -1e30f;
    }

    // in-register online softmax, log2 domain, defer-max (T13)
    float mx = fmaxf(fmaxf(sfr[0][0], sfr[0][1]), fmaxf(sfr[0][2], sfr[0][3]));
#pragma unroll
    for (int nb = 1; nb < 4; ++nb)
      mx = fmaxf(mx, fmaxf(fmaxf(sfr[nb][0], sfr[nb][1]), fmaxf(sfr[nb][2], sfr[nb][3])));
    mx = fmaxf(mx, __shfl_xor(mx, 16, 64));
    mx = fmaxf(mx, __shfl_xor(mx, 32, 64));
    if (!__all(mx <= mrun + 8.0f)) {  // rare rescale path
      float mnew = fmaxf(mrun, mx);
      float sc = exp2f(mrun - mnew);
      mrun = mnew;
      lrun *= sc;
      float scb[4];
#pragma unroll
      for (int r = 0; r < 4; ++r) scb[r] = __shfl(sc, g * 4 + r, 64);
#pragma unroll
      for (int nb = 0; nb < 4; ++nb)
#pragma unroll
        for (int r = 0; r < 4; ++r) acco[nb][r] *= scb[r];
    }
    float rs = 0.f;
#pragma unroll
    for (int nb = 0; nb < 4; ++nb)
#pragma unroll
      for (int r = 0; r < 4; ++r) {
        float p = exp2f(sfr[nb][r] - mrun);
        sfr[nb][r] = p;
        rs += p;
      }
    rs += __shfl_xor(rs, 16, 64);
    rs += __shfl_xor(rs, 32, 64);
    lrun += rs;

    // P -> wave-private LDS (packed 4x bf16 = consecutive k), 16B-slot swizzle
#pragma unroll
    for (int nb = 0; nb < 4; ++nb) {
      short4 pv;
      pv.x = tobf(sfr[nb][0]);
      pv.y = tobf(sfr[nb][1]);
      pv.z = tobf(sfr[nb][2]);
      pv.w = tobf(sfr[nb][3]);
      int pslot = (nb * 2 + (g >> 1)) ^ swz(c);
      *(short4*)&Pw[c * 64 + pslot * 8 + (g & 1) * 4] = pv;
    }

    // PV: O[q][d] += P * V
    __builtin_amdgcn_s_setprio(1);
#pragma unroll
    for (int kk = 0; kk < 2; ++kk) {
      short8 ap = *(const short8*)&Pw[c * 64 + (((kk * 4 + g) ^ swz(c)) * 8)];
#pragma unroll
      for (int nb = 0; nb < 4; ++nb)
        acco[nb] = __builtin_amdgcn_mfma_f32_16x16x32_bf16(ap, bv[kk][nb], acco[nb], 0, 0, 0);
    }
    __builtin_amdgcn_s_setprio(0);

    // counted-vmcnt barrier (T4): tile j+1 landed, tile j+2 stays in flight
    if (pf2) asm volatile("s_waitcnt vmcnt(4)" ::: "memory");
    else     asm volatile("s_waitcnt vmcnt(0)" ::: "memory");
    __builtin_amdgcn_s_barrier();
    __builtin_amdgcn_sched_barrier(0);

    cur = (cur == 2) ? 0 : cur + 1;
    s2 = (s2 == 2) ? 0 : s2 + 1;
    pk2 += 98304;
    pv2 += 64;
  }

  // epilogue: broadcast 1/l to acco row layout, store bf16
  float li = 1.0f / lrun;
  float lb[4];
#pragma unroll
  for (int r = 0; r < 4; ++r) lb[r] = __shfl(li, g * 4 + r, 64);
#pragma unroll
  for (int nb = 0; nb < 4; ++nb)
#pragma unroll
    for (int r = 0; r < 4; ++r) {
      int m = b * 2048 + qt * 64 + w * 16 + g * 4 + r;
      int n = h * 64 + nb * 16 + c;
      aout[(size_t)m * 1024 + n] = tobf(acco[nb][r] * lb[r]);
    }
}

// ---------- launch ----------
extern "C" void kernel_launch(void* const* d_in, const int* in_sizes, int n_in,
                              void* d_out, int out_size, void* d_ws, size_t ws_size,
                              hipStream_t stream) {
  const float* x    = (const float*)d_in[0];
  const float* Wqkv = (const float*)d_in[1];
  const float* bqkv = (const float*)d_in[2];
  const float* Wout = (const float*)d_in[3];
  const float* bout = (const float*)d_in[4];

  char* ws = (char*)d_ws;
  short* xb    = (short*)ws; ws += 8388608;    // x bf16 [4096][1024]
  short* WqkvT = (short*)ws; ws += 3145728;    // [1536][1024] bf16
  short* WoutT = (short*)ws; ws += 2097152;    // [1024][1024] bf16
  short* qkvb  = (short*)ws; ws += 12582912;   // [4096][1536] bf16 (post-RoPE)
  short* attnb = (short*)ws; ws += 8388608;    // [4096][1024] bf16
  short* vTb   = (short*)ws; ws += 2097152;    // [8][64][2048] bf16 (V transposed)
  float* cost  = (float*)ws; ws += 262144;     // [2048][32]
  float* sint  = (float*)ws; ws += 262144;

  prep_k<<<1920, 256, 0, stream>>>(x, xb, Wqkv, WqkvT, Wout, WoutT, cost, sint);
  gemm128_k<0><<<384, 256, 0, stream>>>(xb, WqkvT, bqkv, (void*)qkvb, 4096, 1536, 1024, cost, sint);
  vtrans_k<<<256, 256, 0, stream>>>(qkvb, vTb);
  attn_k<<<1024, 256, 0, stream>>>(qkvb, vTb, attnb);
  gemm128_k<1><<<256, 256, 0, stream>>>(attnb, WoutT, bout, d_out, 4096, 1024, 1024, cost, sint);
}